// Round 4
// baseline (264.213 us; speedup 1.0000x reference)
//
#include <hip/hip_runtime.h>
#include <hip/hip_bf16.h>

// ResultParser: match each GT center to nearest same-batch pred, then per
// matched location gather per-channel 3x3-max + bilinear sample from params,
// concat -> out (NGT, 2C) fp32, plus centers_pred (NGT,2) = [flat%W, flat/W].
//
// Evidence log:
//  R1: reading params as bf16 -> NaN output  => params is fp32.
//  R2/R3: bf16 output writes -> absmax 62.488 = my centers values leaking into
//         chunk 0 when the harness reads fp32  => OUTPUT IS FP32.
// So: fp32 in (runtime-verified), fp32 out. Dims derived at runtime:
//   NGT = in_sizes[2], NPRED = in_sizes[4], C = 2*in_sizes[0]/in_sizes[1],
//   P = in_sizes[1]/2 = B*HW; device: B = vgt_bids[NGT-1]+1, HW=P/B, W=isqrt(HW).

__device__ __forceinline__ float loadF(const void* p, long long i, bool f32) {
    if (f32) return ((const float*)p)[i];
    return __bfloat162float(((const __hip_bfloat16*)p)[i]);
}

__device__ __forceinline__ int loadI(const void* p, int i, bool packed16) {
    if (!packed16) return ((const int*)p)[i];
    return (int)lrintf(__bfloat162float(((const __hip_bfloat16*)p)[i]));
}

__global__ __launch_bounds__(256) void ResultParser_43645457662371_kernel(
    const void* __restrict__ params,     // (B,C,H,W) fp32 (or bf16, detected)
    const void* __restrict__ offsets,    // (B,2,H,W) fp32 (or bf16, detected)
    const void* __restrict__ vgt_bids,   // (NGT,)   int32 (or bf16, detected)
    const void* __restrict__ vgt_centers,// (NGT,2)
    const void* __restrict__ pred_bids,  // (NPRED,)
    const void* __restrict__ pred_cyxs,  // (NPRED,2)
    float* __restrict__ out,             // NGT*2C + NGT*2, fp32
    int NGT, int NPRED, int C, long long P)
{
    const int gt  = blockIdx.x;
    const int tid = threadIdx.x;

    // ---- Phase 0: runtime dtype detection (block-uniform flags) ----
    __shared__ int s_flags;              // bit0: params fp32, bit1: offsets fp32,
                                         // bits 2..5: int buffer is bf16-packed
    if (tid == 0) s_flags = 0;
    __syncthreads();
    {
        int f = 0;
        // float buffers: bf16 view of an fp32 buffer shows huge/NaN values
        const __hip_bfloat16* pb = (const __hip_bfloat16*)params;
        for (int i = tid; i < 2048; i += 256)
            if (!(fabsf(__bfloat162float(pb[i])) < 1e4f)) f |= 1;
        const __hip_bfloat16* ob = (const __hip_bfloat16*)offsets;
        for (int i = tid; i < 2048; i += 256)
            if (!(fabsf(__bfloat162float(ob[i])) < 1e4f)) f |= 2;
        // int buffers: genuine int32 values are tiny; bf16-packed pairs read as
        // int32 are >= 2^29 for any nonzero bf16 in the high half
        const unsigned* b2 = (const unsigned*)vgt_bids;
        for (int i = tid; i < NGT; i += 256)      if (b2[i] > (1u<<20)) f |= 4;
        const unsigned* b3 = (const unsigned*)vgt_centers;
        for (int i = tid; i < 2*NGT; i += 256)    if (b3[i] > (1u<<20)) f |= 8;
        const unsigned* b4 = (const unsigned*)pred_bids;
        for (int i = tid; i < NPRED; i += 256)    if (b4[i] > (1u<<20)) f |= 16;
        const unsigned* b5 = (const unsigned*)pred_cyxs;
        for (int i = tid; i < 2*NPRED; i += 256)  if (b5[i] > (1u<<20)) f |= 32;
        if (f) atomicOr(&s_flags, f);
    }
    __syncthreads();
    const int  flags = s_flags;
    const bool f32p = (flags & 1), f32o = (flags & 2);
    const bool pk2 = (flags & 4), pk3 = (flags & 8), pk4 = (flags & 16), pk5 = (flags & 32);

    // ---- Derived dims (block-uniform) ----
    const int B  = loadI(vgt_bids, NGT - 1, pk2) + 1;
    const long long HW = P / (long long)B;
    int W = (int)(sqrtf((float)HW) + 0.5f);
    while ((long long)W * W > HW) --W;
    while ((long long)(W + 1) * (W + 1) <= HW) ++W;
    const int H = (int)(HW / W);

    const int gb = loadI(vgt_bids, gt, pk2);
    const int gy = loadI(vgt_centers, 2 * gt + 0, pk3);
    const int gx = loadI(vgt_centers, 2 * gt + 1, pk3);

    // ---- Phase A: nearest same-batch pred; (d2, j) lexicographic min ----
    unsigned long long best = ~0ull;
    for (int j = tid; j < NPRED; j += 256) {
        int pb = loadI(pred_bids, j, pk4);
        long long dy = loadI(pred_cyxs, 2 * j + 0, pk5) - gy;
        long long dx = loadI(pred_cyxs, 2 * j + 1, pk5) - gx;
        unsigned long long d2 = (unsigned long long)(dy * dy + dx * dx);
        unsigned long long key = (pb == gb) ? ((d2 << 32) | (unsigned)j) : ~0ull;
        if (key < best) best = key;
    }
    __shared__ unsigned long long sh[256];
    sh[tid] = best;
    __syncthreads();
    for (int s = 128; s > 0; s >>= 1) {
        if (tid < s && sh[tid + s] < sh[tid]) sh[tid] = sh[tid + s];
        __syncthreads();
    }
    const unsigned long long ball = sh[0];
    const int j = (ball == ~0ull) ? 0 : (int)(ball & 0xFFFFFFFFull);

    int cy = loadI(pred_cyxs, 2 * j + 0, pk5); cy = min(max(cy, 0), H - 1);
    int cx = loadI(pred_cyxs, 2 * j + 1, pk5); cx = min(max(cx, 0), W - 1);
    const int flat = cy * W + cx;

    // ---- Per-GT scalars (redundant per thread; cheap) ----
    int nb[9];
    #pragma unroll
    for (int k = 0; k < 9; ++k) {
        int dy = k / 3 - 1, dx = k % 3 - 1;
        int yy = min(max(cy + dy, 0), H - 1);
        int xx = min(max(cx + dx, 0), W - 1);
        nb[k] = yy * W + xx;
    }

    const float offy = loadF(offsets, ((long long)gb * 2 + 0) * HW + flat, f32o);
    const float offx = loadF(offsets, ((long long)gb * 2 + 1) * HW + flat, f32o);
    const float yf = (float)cy + offy;
    const float xf = (float)cx + offx;
    const float y0f = floorf(yf), x0f = floorf(xf);
    const float wy1 = yf - y0f, wx1 = xf - x0f;
    const float wy0 = 1.0f - wy1, wx0 = 1.0f - wx1;

    int   ci[4];
    float cw[4];
    {
        const float ys[2] = {y0f, y0f + 1.0f};
        const float xs[2] = {x0f, x0f + 1.0f};
        const float wy[2] = {wy0, wy1};
        const float wx[2] = {wx0, wx1};
        #pragma unroll
        for (int a = 0; a < 2; ++a) {
            #pragma unroll
            for (int b2 = 0; b2 < 2; ++b2) {
                const float yy = ys[a], xx = xs[b2];
                const bool inb = (yy >= 0.0f) && (yy <= (float)(H - 1)) &&
                                 (xx >= 0.0f) && (xx <= (float)(W - 1));
                const int yi = (int)fminf(fmaxf(yy, 0.0f), (float)(H - 1));
                const int xi = (int)fminf(fmaxf(xx, 0.0f), (float)(W - 1));
                ci[a * 2 + b2] = yi * W + xi;
                cw[a * 2 + b2] = inb ? (wy[a] * wx[b2]) : 0.0f; // OOB corner -> 0
            }
        }
    }

    // ---- Phase B: per-channel gather (3x3 max + bilinear), fp32 out ----
    const long long base_b = (long long)gb * C * HW;
    const long long orow   = (long long)gt * (2 * C);
    for (int c = tid; c < C; c += 256) {
        const long long chbase = base_b + (long long)c * HW;
        float mx = -3.4e38f;
        #pragma unroll
        for (int k = 0; k < 9; ++k)
            mx = fmaxf(mx, loadF(params, chbase + nb[k], f32p));
        float s = 0.0f;
        #pragma unroll
        for (int k = 0; k < 4; ++k)
            s += cw[k] * loadF(params, chbase + ci[k], f32p);
        out[orow + c]     = s;    // params_pred
        out[orow + C + c] = mx;   // params_pred_max
    }

    // centers_pred row gt: [flat % MAP, flat // MAP]  (MAP == W here)
    if (tid < 2) {
        const int v = (tid == 0) ? (flat % W) : (flat / W);
        out[(long long)NGT * (2 * C) + gt * 2 + tid] = (float)v;
    }
}

extern "C" void kernel_launch(void* const* d_in, const int* in_sizes, int n_in,
                              void* d_out, int out_size, void* d_ws, size_t ws_size,
                              hipStream_t stream) {
    const void* params  = d_in[0];
    const void* offsets = d_in[1];
    const void* vgt_bids    = d_in[2];
    const void* vgt_centers = d_in[3];
    const void* pred_bids   = d_in[4];
    const void* pred_cyxs   = d_in[5];
    float* out = (float*)d_out;

    const int NGT   = in_sizes[2];
    const int NPRED = in_sizes[4];
    // params = B*C*HW elems, offsets = B*2*HW elems -> C = 2 * ratio
    const long long C = 2LL * (long long)in_sizes[0] / (long long)in_sizes[1];
    const long long P = (long long)in_sizes[1] / 2;   // B * HW

    ResultParser_43645457662371_kernel<<<dim3(NGT), dim3(256), 0, stream>>>(
        params, offsets, vgt_bids, vgt_centers, pred_bids, pred_cyxs, out,
        NGT, NPRED, (int)C, P);
}